// Round 3
// baseline (418.523 us; speedup 1.0000x reference)
//
#include <hip/hip_runtime.h>

#define TPB 512
#define P_TH 2
#define GROUPS (TPB / 32)
#define P_BLK (GROUPS * P_TH)   // 32 parents per block

__global__ __launch_bounds__(TPB, 4) void equi_unpool_v3(
    const float* __restrict__ x_mv,    // [Np,32,16]
    const float* __restrict__ x_s,     // [Np,64]
    const float* __restrict__ skip_mv, // [Nc,32,16]
    const float* __restrict__ skip_s,  // [Nc,64]
    const float* __restrict__ w_mv,    // [32,32,9]
    const float* __restrict__ w_s2mv,  // [32,64]
    const float* __restrict__ w_mv2s,  // [64,32]
    const float* __restrict__ w_s2s,   // [64,64]
    const float* __restrict__ b_s,     // [64]
    float* __restrict__ out_mv,        // [Nc,32,16]
    float* __restrict__ out_s,         // [Nc,64]
    int n_parent, int stride)
{
    // Weights packed [i][o][12]: slots 0-8 = w_mv[o][i][b], 9 = w_mv2s[o][i],
    // 10 = w_mv2s[o+32][i], 11 = pad. 48 KB -> 2 blocks/CU.
    // Inner-loop read: 3x ds_read_b128 at lane-stride 48B (8 lanes span all 32
    // banks exactly once -> conflict-free).
    __shared__ float lw[12288];
    __shared__ float lbs[64];

    const int tid = threadIdx.x;
    #pragma unroll
    for (int base = 0; base < 12288; base += TPB) {
        int dst = base + tid;              // dst-linear => conflict-free ds_write
        int t = dst / 12;                  // const divisor -> mul_hi, cheap
        int s = dst - t * 12;
        int oo = t & 31, ii = t >> 5;
        float v = 0.f;
        if (s < 9)        v = w_mv[oo * 288 + ii * 9 + s];
        else if (s == 9)  v = w_mv2s[oo * 32 + ii];
        else if (s == 10) v = w_mv2s[(oo + 32) * 32 + ii];
        lw[dst] = v;
    }
    if (tid < 64) lbs[tid] = b_s[tid];
    __syncthreads();

    const int o = tid & 31;                       // output channel
    const int g = tid >> 5;                       // parent group
    const int pA = blockIdx.x * P_BLK + g * P_TH;
    if (pA >= n_parent) return;
    const bool hasB = (pA + 1 < n_parent);
    const int pB = hasB ? pA + 1 : pA;

    const float4* xA = (const float4*)(x_mv + (size_t)pA * 512);
    const float4* xB = (const float4*)(x_mv + (size_t)pB * 512);

    float a0[16], a1[16];
    #pragma unroll
    for (int j = 0; j < 16; ++j) { a0[j] = 0.f; a1[j] = 0.f; }
    float sA0 = 0.f, sA1 = 0.f, sB0 = 0.f, sB1 = 0.f;

    // register double-buffer: iter 0 preloaded, next iter prefetched in-body
    float4 cA0 = xA[0], cA1 = xA[1], cA2 = xA[2], cA3 = xA[3];
    float4 cB0 = xB[0], cB1 = xB[1], cB2 = xB[2], cB3 = xB[3];

    #pragma unroll 4
    for (int i = 0; i < 32; ++i) {
        const int nx = ((i + 1) & 31) * 4;        // wraps to 0 on last iter (valid, unused)
        float4 nA0 = xA[nx + 0], nA1 = xA[nx + 1], nA2 = xA[nx + 2], nA3 = xA[nx + 3];
        float4 nB0 = xB[nx + 0], nB1 = xB[nx + 1], nB2 = xB[nx + 2], nB3 = xB[nx + 3];

        const float* wp = &lw[(i * 32 + o) * 12];
        float4 wa = *(const float4*)(wp + 0);     // w0..w3
        float4 wb = *(const float4*)(wp + 4);     // w4..w7
        float4 wc = *(const float4*)(wp + 8);     // w8, wm0, wm1, pad

        // parent A
        a0[0]  += cA0.x * wa.x;
        a0[1]  += cA0.y * wa.y + cA0.x * wb.y;
        a0[2]  += cA0.z * wa.y;
        a0[3]  += cA0.w * wa.y;
        a0[4]  += cA1.x * wa.y;
        a0[5]  += cA1.y * wa.z + cA0.z * wb.z;
        a0[6]  += cA1.z * wa.z + cA0.w * wb.z;
        a0[7]  += cA1.w * wa.z + cA1.x * wb.z;
        a0[8]  += cA2.x * wa.z;
        a0[9]  += cA2.y * wa.z;
        a0[10] += cA2.z * wa.z;
        a0[11] += cA2.w * wa.w + cA2.x * wb.w;
        a0[12] += cA3.x * wa.w + cA2.y * wb.w;
        a0[13] += cA3.y * wa.w + cA2.z * wb.w;
        a0[14] += cA3.z * wa.w;
        a0[15] += cA3.w * wb.x + cA3.z * wc.x;
        sA0 += cA0.x * wc.y;
        sA1 += cA0.x * wc.z;
        // parent B
        a1[0]  += cB0.x * wa.x;
        a1[1]  += cB0.y * wa.y + cB0.x * wb.y;
        a1[2]  += cB0.z * wa.y;
        a1[3]  += cB0.w * wa.y;
        a1[4]  += cB1.x * wa.y;
        a1[5]  += cB1.y * wa.z + cB0.z * wb.z;
        a1[6]  += cB1.z * wa.z + cB0.w * wb.z;
        a1[7]  += cB1.w * wa.z + cB1.x * wb.z;
        a1[8]  += cB2.x * wa.z;
        a1[9]  += cB2.y * wa.z;
        a1[10] += cB2.z * wa.z;
        a1[11] += cB2.w * wa.w + cB2.x * wb.w;
        a1[12] += cB3.x * wa.w + cB2.y * wb.w;
        a1[13] += cB3.y * wa.w + cB2.z * wb.w;
        a1[14] += cB3.z * wa.w;
        a1[15] += cB3.w * wb.x + cB3.z * wc.x;
        sB0 += cB0.x * wc.y;
        sB1 += cB0.x * wc.z;

        cA0 = nA0; cA1 = nA1; cA2 = nA2; cA3 = nA3;
        cB0 = nB0; cB1 = nB1; cB2 = nB2; cB3 = nB3;
    }

    // ---- scalar inputs: s2mv (into a*[0]) and s2s ----
    const float4* xsA = (const float4*)(x_s + (size_t)pA * 64);
    const float4* xsB = (const float4*)(x_s + (size_t)pB * 64);
    const float4* wmv = (const float4*)(w_s2mv + (size_t)o * 64);
    const float4* wsa = (const float4*)(w_s2s + (size_t)o * 64);
    const float4* wsb = (const float4*)(w_s2s + (size_t)(o + 32) * 64);
    #pragma unroll 4
    for (int sc = 0; sc < 16; ++sc) {
        float4 xa = xsA[sc], xb = xsB[sc];
        float4 m = wmv[sc], wa = wsa[sc], wb = wsb[sc];
        a0[0] += xa.x * m.x + xa.y * m.y + xa.z * m.z + xa.w * m.w;
        a1[0] += xb.x * m.x + xb.y * m.y + xb.z * m.z + xb.w * m.w;
        sA0 += xa.x * wa.x + xa.y * wa.y + xa.z * wa.z + xa.w * wa.w;
        sA1 += xa.x * wb.x + xa.y * wb.y + xa.z * wb.z + xa.w * wb.w;
        sB0 += xb.x * wa.x + xb.y * wa.y + xb.z * wa.z + xb.w * wa.w;
        sB1 += xb.x * wb.x + xb.y * wb.y + xb.z * wb.z + xb.w * wb.w;
    }
    float bs0 = lbs[o], bs1 = lbs[o + 32];
    sA0 += bs0; sA1 += bs1; sB0 += bs0; sB1 += bs1;

    // ---- epilogue: broadcast to children, add skip, store (coalesced) ----
    for (int r = 0; r < stride; ++r) {
        size_t c = (size_t)pA * stride + r;
        const float4* sk = (const float4*)(skip_mv + c * 512 + o * 16);
        float4* om = (float4*)(out_mv + c * 512 + o * 16);
        float4 k0 = sk[0], k1 = sk[1], k2 = sk[2], k3 = sk[3];
        om[0] = make_float4(k0.x + a0[0],  k0.y + a0[1],  k0.z + a0[2],  k0.w + a0[3]);
        om[1] = make_float4(k1.x + a0[4],  k1.y + a0[5],  k1.z + a0[6],  k1.w + a0[7]);
        om[2] = make_float4(k2.x + a0[8],  k2.y + a0[9],  k2.z + a0[10], k2.w + a0[11]);
        om[3] = make_float4(k3.x + a0[12], k3.y + a0[13], k3.z + a0[14], k3.w + a0[15]);
        out_s[c * 64 + o]      = skip_s[c * 64 + o] + sA0;
        out_s[c * 64 + o + 32] = skip_s[c * 64 + o + 32] + sA1;
    }
    if (hasB) {
        for (int r = 0; r < stride; ++r) {
            size_t c = (size_t)pB * stride + r;
            const float4* sk = (const float4*)(skip_mv + c * 512 + o * 16);
            float4* om = (float4*)(out_mv + c * 512 + o * 16);
            float4 k0 = sk[0], k1 = sk[1], k2 = sk[2], k3 = sk[3];
            om[0] = make_float4(k0.x + a1[0],  k0.y + a1[1],  k0.z + a1[2],  k0.w + a1[3]);
            om[1] = make_float4(k1.x + a1[4],  k1.y + a1[5],  k1.z + a1[6],  k1.w + a1[7]);
            om[2] = make_float4(k2.x + a1[8],  k2.y + a1[9],  k2.z + a1[10], k2.w + a1[11]);
            om[3] = make_float4(k3.x + a1[12], k3.y + a1[13], k3.z + a1[14], k3.w + a1[15]);
            out_s[c * 64 + o]      = skip_s[c * 64 + o] + sB0;
            out_s[c * 64 + o + 32] = skip_s[c * 64 + o + 32] + sB1;
        }
    }
}

extern "C" void kernel_launch(void* const* d_in, const int* in_sizes, int n_in,
                              void* d_out, int out_size, void* d_ws, size_t ws_size,
                              hipStream_t stream) {
    const float* x_mv    = (const float*)d_in[0];
    const float* x_s     = (const float*)d_in[1];
    const float* skip_mv = (const float*)d_in[2];
    const float* skip_s  = (const float*)d_in[3];
    const float* w_mv    = (const float*)d_in[4];
    const float* w_s2mv  = (const float*)d_in[5];
    const float* w_mv2s  = (const float*)d_in[6];
    const float* w_s2s   = (const float*)d_in[7];
    const float* b_s     = (const float*)d_in[8];

    const int n_parent = in_sizes[0] / 512;   // [Np,32,16]
    const int n_child  = in_sizes[2] / 512;   // [Nc,32,16]
    const int stride   = n_child / n_parent;

    float* out_mv = (float*)d_out;
    float* out_s  = out_mv + (size_t)n_child * 512;

    const int blocks = (n_parent + P_BLK - 1) / P_BLK;
    equi_unpool_v3<<<blocks, TPB, 0, stream>>>(
        x_mv, x_s, skip_mv, skip_s, w_mv, w_s2mv, w_mv2s, w_s2s, b_s,
        out_mv, out_s, n_parent, stride);
}